// Round 13
// baseline (232.883 us; speedup 1.0000x reference)
//
#include <hip/hip_runtime.h>
#include <hip/hip_bf16.h>

// B=1024, S=200, IN1=IN2=H=128
constexpr int S_ = 200;

typedef __attribute__((ext_vector_type(8))) short short8_t;
typedef __attribute__((ext_vector_type(4))) float float4_t;

__device__ inline unsigned short f2bf(float f) {
  unsigned int u = __float_as_uint(f);
  u += 0x7FFFu + ((u >> 16) & 1u);   // RTE
  return (unsigned short)(u >> 16);
}
__device__ inline unsigned int pk2(float x, float y) {
  return (unsigned int)f2bf(x) | ((unsigned int)f2bf(y) << 16);
}

// ---- k0: blocks 0..511: w2h = z@W2+b2 -> ws. blocks 512..519: W1 -> frags. ----
__global__ __launch_bounds__(256) void prep_kernel(
    const float* __restrict__ z, const float* __restrict__ W1,
    const float* __restrict__ W2, const float* __restrict__ b2,
    float* __restrict__ w2h_out, short8_t* __restrict__ frag_out) {
  const int blk = blockIdx.x, t = threadIdx.x;
  if (blk < 512) {
    const int gid = blk * 256 + t;
    const int b = gid >> 7, h = gid & 127;
    const float* zb = z + (size_t)b * 128;
    float acc = b2[h];
    #pragma unroll 8
    for (int d = 0; d < 128; ++d) acc = fmaf(zb[d], W2[d * 128 + h], acc);
    w2h_out[gid] = acc;
  } else {
    const int fid = (blk - 512) * 256 + t;        // 0..2047
    const int lane = fid & 63, kk = (fid >> 6) & 3, nh = fid >> 8;
    const int c = lane & 15, kb = lane >> 4;
    const int h = nh * 16 + c;
    union { short8_t s8; unsigned int u[4]; } cv;
    #pragma unroll
    for (int jp = 0; jp < 4; ++jp) {
      const int k = kk * 32 + kb * 8 + jp * 2;
      cv.u[jp] = pk2(W1[k * 128 + h], W1[(k + 1) * 128 + h]);
    }
    frag_out[fid] = cv.s8;
  }
}

// ---- k1: (b, half of 100 rows): logits + partial softmax + partial pool. ----
__global__ __launch_bounds__(256, 4) void logits_pool_kernel(
    const float* __restrict__ input, const int* __restrict__ mask,
    const float* __restrict__ w2h, const float* __restrict__ V,
    const float* __restrict__ bV, const short8_t* __restrict__ frag,
    float* __restrict__ P_out, float* __restrict__ mz_out) {
  __shared__ short8_t frag_lds[2048];    // 32 KB FULL table [nh(8)][kk(4)][lane(64)]
  __shared__ float att_part[2][112];
  __shared__ float att_w[112];
  __shared__ float pool[2][128];
  __shared__ float redA[4], redB[4];

  const int t = threadIdx.x;
  const int b = blockIdx.x >> 1, half = blockIdx.x & 1;
  const int lane = t & 63, wid = t >> 6;
  const int c = lane & 15, kb = lane >> 4;
  const int rq = wid >> 1, hh_i = wid & 1, hh = hh_i * 64;
  const int rbase = half * 100;
  const float* inb = input + (size_t)b * (S_ * 128);

  // stage full frag table (8 x 256 coalesced 16B loads)
  #pragma unroll
  for (int i = 0; i < 8; ++i) frag_lds[t + i * 256] = frag[t + i * 256];

  const int maskv = (t < 100) ? mask[(size_t)b * S_ + rbase + t] : 0;
  const float bVv = bV[0];

  float w2v[4], vv[4];
  #pragma unroll
  for (int n = 0; n < 4; ++n) {
    w2v[n] = w2h[b * 128 + hh + n * 16 + c];
    vv[n] = V[hh + n * 16 + c];
  }

  // tiles: rq=0 -> rel tiles {0,2,4,6}; rq=1 -> {1,3,5}; rows rel 0..111
  const int ntiles = rq ? 3 : 4;
  float4 pa[4][2];
  {
    const int arow = rbase + rq * 16 + c;
    const int lrow = arow < S_ ? arow : (S_ - 1);
    const float* rp = input + (size_t)b * (S_ * 128) + lrow * 128 + kb * 8;
    #pragma unroll
    for (int kk = 0; kk < 4; ++kk) {
      pa[kk][0] = *reinterpret_cast<const float4*>(rp + kk * 32);
      pa[kk][1] = *reinterpret_cast<const float4*>(rp + kk * 32 + 4);
    }
  }
  __syncthreads();   // frag_lds ready

  for (int i = 0; i < ntiles; ++i) {
    const int rt = rq + 2 * i;
    short8_t a[4];
    #pragma unroll
    for (int kk = 0; kk < 4; ++kk) {
      union { short8_t s8; unsigned int u[4]; } cv;
      cv.u[0] = pk2(pa[kk][0].x, pa[kk][0].y);
      cv.u[1] = pk2(pa[kk][0].z, pa[kk][0].w);
      cv.u[2] = pk2(pa[kk][1].x, pa[kk][1].y);
      cv.u[3] = pk2(pa[kk][1].z, pa[kk][1].w);
      a[kk] = cv.s8;
    }
    if (i + 1 < ntiles) {
      const int arow = rbase + (rt + 2) * 16 + c;
      const int lrow = arow < S_ ? arow : (S_ - 1);
      const float* rp = inb + lrow * 128 + kb * 8;
      #pragma unroll
      for (int kk = 0; kk < 4; ++kk) {
        pa[kk][0] = *reinterpret_cast<const float4*>(rp + kk * 32);
        pa[kk][1] = *reinterpret_cast<const float4*>(rp + kk * 32 + 4);
      }
    }
    float4_t acc[4] = {{0.f, 0.f, 0.f, 0.f}, {0.f, 0.f, 0.f, 0.f},
                       {0.f, 0.f, 0.f, 0.f}, {0.f, 0.f, 0.f, 0.f}};
    #pragma unroll
    for (int kk = 0; kk < 4; ++kk) {
      #pragma unroll
      for (int n = 0; n < 4; ++n)
        acc[n] = __builtin_amdgcn_mfma_f32_16x16x32_bf16(
            a[kk], frag_lds[((hh_i * 4 + n) * 4 + kk) * 64 + lane], acc[n], 0, 0, 0);
    }
    // tanh + V-dot; D layout: col = n*16+c, rel row = rt*16 + kb*4 + r
    #pragma unroll
    for (int r = 0; r < 4; ++r) {
      const int rel = rt * 16 + kb * 4 + r;
      float p = 0.f;
      #pragma unroll
      for (int n = 0; n < 4; ++n) {
        const float x = acc[n][r] + w2v[n];
        const float e = __expf(x + x);            // inf-safe: u -> +/-1
        const float u = 1.f - __fdividef(2.f, e + 1.f);
        p = fmaf(u, vv[n], p);
      }
      p += __shfl_xor(p, 1);
      p += __shfl_xor(p, 2);
      p += __shfl_xor(p, 4);
      p += __shfl_xor(p, 8);
      if (c == 0) att_part[hh_i][rel] = p;
    }
  }
  __syncthreads();

  // partial masked softmax over this half's 100 rows
  float logit = -3.0e38f;
  if (t < 100) {
    logit = att_part[0][t] + att_part[1][t] + bVv;
    if (maskv == 0) logit = -1e10f;
  }
  {
    float m = logit;
    #pragma unroll
    for (int off = 32; off; off >>= 1) m = fmaxf(m, __shfl_xor(m, off));
    if (lane == 0) redA[wid] = m;
  }
  __syncthreads();
  const float M = fmaxf(fmaxf(redA[0], redA[1]), fmaxf(redA[2], redA[3]));
  {
    const float ee = (t < 100) ? __expf(logit - M) : 0.f;
    float sg = ee;
    #pragma unroll
    for (int off = 32; off; off >>= 1) sg += __shfl_xor(sg, off);
    if (lane == 0) redB[wid] = sg;
    if (t < 100) att_w[t] = ee;
  }
  __syncthreads();
  const float Z = redB[0] + redB[1] + redB[2] + redB[3];

  // partial pool from L2-hot rows: thread = (d, ph of 50 rows)
  {
    const int d = t & 127, ph = t >> 7;
    const float* pp = inb + (size_t)(rbase + ph * 50) * 128 + d;
    float a0 = 0.f;
    #pragma unroll 5
    for (int s = 0; s < 50; ++s) a0 = fmaf(att_w[ph * 50 + s], pp[(size_t)s * 128], a0);
    pool[ph][d] = a0;
  }
  __syncthreads();
  if (t < 128)
    P_out[((size_t)b * 2 + half) * 128 + t] = pool[0][t] + pool[1][t];
  if (t == 0) {
    mz_out[((size_t)b * 2 + half) * 2 + 0] = M;
    mz_out[((size_t)b * 2 + half) * 2 + 1] = Z;
  }
}

// ---- k2: merge two halves per b (flash rescale). 512 blocks x 256. ----
__global__ __launch_bounds__(256) void merge_kernel(
    const float* __restrict__ P, const float* __restrict__ mz,
    float* __restrict__ out) {
  const int gid = blockIdx.x * 256 + threadIdx.x;   // 131072 = 1024*128
  const int b = gid >> 7, d = gid & 127;
  const float m0 = mz[b * 4 + 0], z0 = mz[b * 4 + 1];
  const float m1 = mz[b * 4 + 2], z1 = mz[b * 4 + 3];
  const float M = fmaxf(m0, m1);
  const float s0 = __expf(m0 - M), s1 = __expf(m1 - M);
  const float denom = s0 * z0 + s1 * z1;            // >= 1 always
  out[gid] = __fdividef(
      fmaf(s0, P[(size_t)(b * 2) * 128 + d], s1 * P[(size_t)(b * 2 + 1) * 128 + d]),
      denom);
}

extern "C" void kernel_launch(void* const* d_in, const int* in_sizes, int n_in,
                              void* d_out, int out_size, void* d_ws, size_t ws_size,
                              hipStream_t stream) {
  const float* input = (const float*)d_in[0];
  const float* z     = (const float*)d_in[1];
  const int*   mask  = (const int*)d_in[2];
  const float* W1    = (const float*)d_in[3];
  const float* W2    = (const float*)d_in[4];
  const float* b2    = (const float*)d_in[5];
  const float* V     = (const float*)d_in[6];
  const float* bV    = (const float*)d_in[7];
  float* out = (float*)d_out;

  // ws layout: [0,32K) frags | [32K,544K) w2h | [544K,1568K) P | [1568K,1584K) mz
  char* ws = (char*)d_ws;
  short8_t* frag_ws = (short8_t*)ws;
  float* w2h_ws = (float*)(ws + 32768);
  float* P_ws   = (float*)(ws + 557056);
  float* mz_ws  = (float*)(ws + 1605632);

  prep_kernel<<<520, 256, 0, stream>>>(z, W1, W2, b2, w2h_ws, frag_ws);
  logits_pool_kernel<<<2048, 256, 0, stream>>>(input, mask, w2h_ws, V, bV,
                                               frag_ws, P_ws, mz_ws);
  merge_kernel<<<512, 256, 0, stream>>>(P_ws, mz_ws, out);
}